// Round 17
// baseline (78.375 us; speedup 1.0000x reference)
//
#include <hip/hip_runtime.h>
#include <cmath>

#define N_IMG 128
#define MAX_R 36
#define N_CAP 128
#define MAX_W 32
#define DIM   512
#define NEGV  -1e30f

typedef unsigned short u16;
typedef unsigned int   u32;
typedef unsigned char  u8;
typedef __attribute__((ext_vector_type(4))) int i32x4;

#define NI_ELEMS (N_IMG * MAX_R * DIM)   // 2359296
#define NC_ELEMS (N_CAP * MAX_W * DIM)   // 2097152

// i8 chunk geometry (bytes)
#define A_CHUNK 18432   // imgs per (g,kb):  [h 144x64][l 144x64]
#define B_CHUNK 16384   // caps per (cg,kb): [h 128x64][l 128x64]
// LDS: A double-buffered (2x18432) + B SINGLE-buffered (16384) = 53248
// -> 3 blocks/CU. launch_bounds(256,2): 128 VGPR, no spill (R14/R15 lessons).
#define LDS_BYTES 53248
#define A0_OFF 0
#define A1_OFF 18432
#define B_OFF  36864

__device__ __forceinline__ void gload_lds16(const void* g, void* l) {
    __builtin_amdgcn_global_load_lds(
        (const __attribute__((address_space(1))) void*)g,
        (__attribute__((address_space(3))) void*)l, 16, 0, 0);
}

// ---------------------------------------------------------------------------
// Kernel 0: fp32 -> i16 -> (h,l) i8 split, pre-tiled + pre-swizzled.
// x ~= 2^-12 * (256*h + l). imgs packed 144 rows/tile (no pad), caps 128 rows.
// ---------------------------------------------------------------------------
__global__ __launch_bounds__(256) void convert_kernel(const float* __restrict__ imgs,
                                                      const float* __restrict__ caps,
                                                      u8* __restrict__ imgsT,
                                                      u8* __restrict__ capsT) {
    const size_t ni4 = NI_ELEMS / 4;
    const size_t total4 = (NI_ELEMS + NC_ELEMS) / 4;
    const size_t stride = (size_t)gridDim.x * blockDim.x;
    for (size_t p = (size_t)blockIdx.x * blockDim.x + threadIdx.x; p < total4; p += stride) {
        const bool isImg = p < ni4;
        const float4 v = isImg ? ((const float4*)imgs)[p] : ((const float4*)caps)[p - ni4];
        const int q0 = (int)rintf(fminf(fmaxf(v.x * 4096.f, -32639.f), 32639.f));
        const int q1 = (int)rintf(fminf(fmaxf(v.y * 4096.f, -32639.f), 32639.f));
        const int q2 = (int)rintf(fminf(fmaxf(v.z * 4096.f, -32639.f), 32639.f));
        const int q3 = (int)rintf(fminf(fmaxf(v.w * 4096.f, -32639.f), 32639.f));
        const int h0 = (q0 + 128) >> 8, l0 = q0 - (h0 << 8);
        const int h1 = (q1 + 128) >> 8, l1 = q1 - (h1 << 8);
        const int h2 = (q2 + 128) >> 8, l2 = q2 - (h2 << 8);
        const int h3 = (q3 + 128) >> 8, l3 = q3 - (h3 << 8);
        const u32 hw = (u32)(h0 & 255) | ((u32)(h1 & 255) << 8) |
                       ((u32)(h2 & 255) << 16) | ((u32)(h3 & 255) << 24);
        const u32 lw = (u32)(l0 & 255) | ((u32)(l1 & 255) << 8) |
                       ((u32)(l2 & 255) << 16) | ((u32)(l3 & 255) << 24);
        if (isImg) {
            const int e = (int)(p * 4);
            const int imgRow = e >> 9, k = e & 511;
            const int g = imgRow / 144;
            const int rowT = imgRow - g * 144;
            const int kb = k >> 6, k6 = k & 63;
            const int blk = (k6 >> 4) ^ ((rowT >> 1) & 3);
            const size_t off = (size_t)(g * 8 + kb) * A_CHUNK + rowT * 64 + blk * 16 + (k6 & 15);
            *(u32*)(imgsT + off) = hw;
            *(u32*)(imgsT + off + 9216) = lw;
        } else {
            const int e = (int)((p - ni4) * 4);
            const int R = e >> 9, k = e & 511;
            const int cg = R >> 7, row = R & 127;
            const int kb = k >> 6, k6 = k & 63;
            const int blk = (k6 >> 4) ^ ((row >> 1) & 3);
            const size_t off = (size_t)(cg * 8 + kb) * B_CHUNK + row * 64 + blk * 16 + (k6 & 15);
            *(u32*)(capsT + off) = hw;
            *(u32*)(capsT + off + 8192) = lw;
        }
    }
}

// ---------------------------------------------------------------------------
// Kernel A: per-image Gram via i8 MFMA from imgsT. Exact 3-acc fold.
// ---------------------------------------------------------------------------
__global__ __launch_bounds__(256) void gram_i8_kernel(const u8* __restrict__ imgsT,
                                                      float* __restrict__ G) {
    const int i  = blockIdx.x;
    const int gg = i >> 2;
    const int m  = i & 3;
    const int t = threadIdx.x;
    const int wid = t >> 6;
    const int lane = t & 63;
    const int l15 = lane & 15;
    const int kq = lane >> 4;

    __shared__ __align__(16) u8 sT[2][2][3072];   // [buf][h/l][48 rows x 64]

    const u8* base = imgsT + (size_t)gg * 8 * A_CHUNK + m * 36 * 64;

    auto stage = [&](int kb, int buf) {
        const u8* hsrc = base + (size_t)kb * A_CHUNK;
        {
            const int u = t;
            if (u < 144) gload_lds16(hsrc + u * 16, &sT[buf][0][u * 16]);
            else if (u < 288) gload_lds16(hsrc + 9216 + (u - 144) * 16, &sT[buf][1][(u - 144) * 16]);
        }
        if (t < 32) {
            const int u = 112 + t;
            gload_lds16(hsrc + 9216 + u * 16, &sT[buf][1][u * 16]);
        }
    };

    i32x4 aH[3], aC[3], aL[3];
    #pragma unroll
    for (int mt = 0; mt < 3; ++mt) {
        aH[mt] = (i32x4){0,0,0,0};
        aC[mt] = (i32x4){0,0,0,0};
        aL[mt] = (i32x4){0,0,0,0};
    }

    stage(0, 0);
    __syncthreads();

    const int m18 = 18 * m;
    for (int kb = 0; kb < 8; ++kb) {
        const int buf = kb & 1;
        if (kb < 7) stage(kb + 1, buf ^ 1);
        if (wid < 3) {
            const int brow = wid * 16 + l15;
            const int bblk = kq ^ ((m18 + (brow >> 1)) & 3);
            const i32x4 bh = *(const i32x4*)&sT[buf][0][brow * 64 + bblk * 16];
            const i32x4 bl = *(const i32x4*)&sT[buf][1][brow * 64 + bblk * 16];
            #pragma unroll
            for (int mt = 0; mt < 3; ++mt) {
                const int arow = mt * 16 + l15;
                const int ablk = kq ^ ((m18 + (arow >> 1)) & 3);
                const i32x4 ah = *(const i32x4*)&sT[buf][0][arow * 64 + ablk * 16];
                const i32x4 al = *(const i32x4*)&sT[buf][1][arow * 64 + ablk * 16];
                aH[mt] = __builtin_amdgcn_mfma_i32_16x16x64_i8(ah, bh, aH[mt], 0, 0, 0);
                aC[mt] = __builtin_amdgcn_mfma_i32_16x16x64_i8(ah, bl, aC[mt], 0, 0, 0);
                aC[mt] = __builtin_amdgcn_mfma_i32_16x16x64_i8(al, bh, aC[mt], 0, 0, 0);
                aL[mt] = __builtin_amdgcn_mfma_i32_16x16x64_i8(al, bl, aL[mt], 0, 0, 0);
            }
        }
        __syncthreads();
    }

    if (wid < 3) {
        const int col = wid * 16 + l15;
        if (col < 36) {
            #pragma unroll
            for (int mt = 0; mt < 3; ++mt) {
                #pragma unroll
                for (int e = 0; e < 4; ++e) {
                    const int row = mt * 16 + kq * 4 + e;
                    if (row < 36) {
                        const float g = (float)aH[mt][e] * (1.f / 256.f)
                                      + (float)aC[mt][e] * (1.f / 65536.f)
                                      + (float)aL[mt][e] * (1.f / 16777216.f);
                        G[(size_t)i * 1296 + row * 36 + col] = g;
                    }
                }
            }
        }
    }
}

// ---------------------------------------------------------------------------
// Kernel B: block = 4 images (144 M-rows) x 4 caps (128 N-cols), 4 waves.
// i8 exact split MFMA. One barrier/step; B wave-private single-buffer.
// R16 finding: kernel is VALU/issue-bound (VALUBusy 52 + MfmaUtil 24.5).
// Epilogue top-5 rewritten: 5x iterative global-max (v_max3 tree + quad
// shfl-max + exclude-by-equality, exact since rr-packed values are unique)
// ~170 ops/unit vs ~300 for insert+merge.
// ---------------------------------------------------------------------------
__global__ __launch_bounds__(256, 2) void vsc_mfma_kernel(const u8* __restrict__ imgsT,
                                const u8* __restrict__ capsT,
                                const int* __restrict__ img_lens,
                                const int* __restrict__ cap_lens,
                                const float* __restrict__ G,
                                float* __restrict__ out) {
    extern __shared__ __align__(16) char smem[];
    const int bid = blockIdx.x;
    const int xcd = bid & 7;
    const int r_  = bid >> 3;
    const int g   = (r_ >> 5) * 8 + xcd;   // image tile 0..31 (4 imgs)
    const int cg  = r_ & 31;               // cap group 0..31 (4 caps = 128 rows)
    const int t = threadIdx.x;
    const int wid = t >> 6;                // 0..3
    const int lane = t & 63;
    const int l15 = lane & 15;
    const int kblk = lane >> 4;            // also the epilogue quad index

    const u8* gA = imgsT + (size_t)g * 8 * A_CHUNK;
    const u8* gB = capsT + (size_t)cg * 8 * B_CHUNK;

    // A quarter per wave (into abuf); B own 32-row band (wave-private region)
    auto stageA = [&](int kb, int abuf) {
        const u8* srcA = gA + (size_t)kb * A_CHUNK;
        char* dstA = smem + abuf * A1_OFF;
        const int ub = wid * 288;
        #pragma unroll
        for (int jj = 0; jj < 4; ++jj) {
            const int u = ub + jj * 64 + lane;
            gload_lds16(srcA + u * 16, dstA + u * 16);
        }
        if (lane < 32) {
            const int u = ub + 256 + lane;
            gload_lds16(srcA + u * 16, dstA + u * 16);
        }
    };
    auto stageB = [&](int kb) {
        const u8* srcB = gB + (size_t)kb * B_CHUNK;
        char* dstB = smem + B_OFF;
        #pragma unroll
        for (int jj = 0; jj < 2; ++jj) {
            const int u = wid * 128 + jj * 64 + lane;
            gload_lds16(srcB + u * 16, dstB + u * 16);                  // h
            gload_lds16(srcB + 8192 + u * 16, dstB + 8192 + u * 16);    // l
        }
    };

    i32x4 accH[9][2], accC[9][2];
    #pragma unroll
    for (int mt = 0; mt < 9; ++mt)
        #pragma unroll
        for (int nt = 0; nt < 2; ++nt) {
            accH[mt][nt] = (i32x4){0, 0, 0, 0};
            accC[mt][nt] = (i32x4){0, 0, 0, 0};
        }

    stageA(0, 0);
    stageB(0);

    const int blk16 = (kblk ^ ((l15 >> 1) & 3)) << 4;
    const int baseA = l15 * 64 + blk16;                // + mt*1024 ; h: +0, l: +9216
    const int baseB = (wid * 32 + l15) * 64 + blk16;   // + nt*1024 ; h: B_OFF, l: B_OFF+8192

    for (int kb = 0; kb < 8; ++kb) {
        // own stage(kb) loads landed (issued a full step ago; kb=0 pays once);
        // barrier publishes all waves' A quarters.
        asm volatile("s_waitcnt vmcnt(0)" ::: "memory");
        __builtin_amdgcn_sched_barrier(0);
        __builtin_amdgcn_s_barrier();
        __builtin_amdgcn_sched_barrier(0);

        char* curA = smem + (size_t)(kb & 1) * A1_OFF;

        // A(kb+1) staging can issue NOW: its buffer's readers (step kb-1)
        // all passed the barrier above.
        if (kb < 7) stageA(kb + 1, (kb + 1) & 1);

        // B -> registers (own band only); then own B region is dead.
        const i32x4 bh0 = *(const i32x4*)(smem + B_OFF + baseB);
        const i32x4 bl0 = *(const i32x4*)(smem + B_OFF + 8192 + baseB);
        const i32x4 bh1 = *(const i32x4*)(smem + B_OFF + baseB + 1024);
        const i32x4 bl1 = *(const i32x4*)(smem + B_OFF + 8192 + baseB + 1024);
        asm volatile("s_waitcnt lgkmcnt(0)" ::: "memory");
        __builtin_amdgcn_sched_barrier(0);

        if (kb < 7) stageB(kb + 1);

        __builtin_amdgcn_s_setprio(1);
        #pragma unroll
        for (int mt = 0; mt < 9; ++mt) {
            const i32x4 ah = *(const i32x4*)(curA + baseA + mt * 1024);
            const i32x4 al = *(const i32x4*)(curA + 9216 + baseA + mt * 1024);
            i32x4 lt0 = (i32x4){0, 0, 0, 0};
            i32x4 lt1 = (i32x4){0, 0, 0, 0};
            lt0 = __builtin_amdgcn_mfma_i32_16x16x64_i8(al, bl0, lt0, 0, 0, 0);
            lt1 = __builtin_amdgcn_mfma_i32_16x16x64_i8(al, bl1, lt1, 0, 0, 0);
            accH[mt][0] = __builtin_amdgcn_mfma_i32_16x16x64_i8(ah, bh0, accH[mt][0], 0, 0, 0);
            accH[mt][1] = __builtin_amdgcn_mfma_i32_16x16x64_i8(ah, bh1, accH[mt][1], 0, 0, 0);
            accC[mt][0] = __builtin_amdgcn_mfma_i32_16x16x64_i8(ah, bl0, accC[mt][0], 0, 0, 0);
            accC[mt][0] = __builtin_amdgcn_mfma_i32_16x16x64_i8(al, bh0, accC[mt][0], 0, 0, 0);
            accC[mt][1] = __builtin_amdgcn_mfma_i32_16x16x64_i8(ah, bl1, accC[mt][1], 0, 0, 0);
            accC[mt][1] = __builtin_amdgcn_mfma_i32_16x16x64_i8(al, bh1, accC[mt][1], 0, 0, 0);
            #pragma unroll
            for (int e = 0; e < 4; ++e) {
                accC[mt][0][e] += lt0[e] >> 8;   // truncation bias <= 1.2e-3 s-units
                accC[mt][1][e] += lt1[e] >> 8;
            }
        }
        __builtin_amdgcn_s_setprio(0);
    }

    __syncthreads();   // all LDS reads done; no outstanding staging

    // ---- stage Gram (4 imgs, fp32) into retired staging LDS
    float* sG = (float*)smem;
    {
        const float4* src = (const float4*)(G + (size_t)g * 4 * 1296);
        for (int idx = t; idx < 1296; idx += 256)
            ((float4*)sG)[idx] = src[idx];
    }
    __syncthreads();

    int ilen_[4];
    #pragma unroll
    for (int j = 0; j < 4; ++j) ilen_[j] = img_lens[g * 4 + j];

    #pragma unroll
    for (int nt = 0; nt < 2; ++nt) {
        const int col = wid * 32 + nt * 16 + l15;     // 0..127 cap-word col
        const int c = cg * 4 + (col >> 5);
        const int w = col & 31;
        const int clen = cap_lens[c];
        #pragma unroll
        for (int j = 0; j < 4; ++j) {
            const int mtb = (36 * j) >> 4;            // 0,2,4,6
            const int ilenj = ilen_[j];
            // 12 masked packed candidates (rr in bits 0..5; unique -> exact
            // exclusion-by-equality below)
            float vv[12];
            #pragma unroll
            for (int dm = 0; dm < 3; ++dm) {
                #pragma unroll
                for (int e = 0; e < 4; ++e) {
                    const int mt = mtb + dm;
                    const int r = mt * 16 + kblk * 4 + e;
                    const int rr = r - 36 * j;
                    const float sval = (float)accH[mt][nt][e] * (10.f / 256.f)
                                     + (float)accC[mt][nt][e] * (10.f / 65536.f);
                    vv[dm * 4 + e] = ((unsigned)rr < (unsigned)ilenj)
                        ? __uint_as_float((__float_as_uint(sval) & ~63u) | (u32)rr)
                        : NEGV;
                }
            }
            // 5x iterative global max over the 48 quad values
            float ta[5];
            #pragma unroll
            for (int s = 0; s < 5; ++s) {
                const float m0 = fmaxf(fmaxf(vv[0], vv[1]), vv[2]);
                const float m1 = fmaxf(fmaxf(vv[3], vv[4]), vv[5]);
                const float m2 = fmaxf(fmaxf(vv[6], vv[7]), vv[8]);
                const float m3 = fmaxf(fmaxf(vv[9], vv[10]), vv[11]);
                float q = fmaxf(fmaxf(fmaxf(m0, m1), m2), m3);
                q = fmaxf(q, __shfl_xor(q, 16));
                q = fmaxf(q, __shfl_xor(q, 32));
                ta[s] = q;
                if (s < 4) {
                    #pragma unroll
                    for (int k = 0; k < 12; ++k)
                        vv[k] = (vv[k] == q) ? NEGV : vv[k];
                }
            }
            // softmax over the 5
            const float m = ta[0];
            const float p0 = 1.f;
            const float p1 = __expf(ta[1] - m);
            const float p2 = __expf(ta[2] - m);
            const float p3 = __expf(ta[3] - m);
            const float p4 = __expf(ta[4] - m);
            const float sum = p0 + p1 + p2 + p3 + p4;
            const float num = p0 * ta[0] + p1 * ta[1] + p2 * ta[2] + p3 * ta[3] + p4 * ta[4];
            const int r0 = __float_as_uint(ta[0]) & 63;
            const int r1 = __float_as_uint(ta[1]) & 63;
            const int r2 = __float_as_uint(ta[2]) & 63;
            const int r3 = __float_as_uint(ta[3]) & 63;
            const int r4 = __float_as_uint(ta[4]) & 63;
            const float* gj = sG + j * 1296;
            const float pa = (kblk == 0) ? p0 : (kblk == 1) ? p1 : (kblk == 2) ? p2 : p3;
            const int   ra = (kblk == 0) ? r0 : (kblk == 1) ? r1 : (kblk == 2) ? r2 : r3;
            const float* grow = gj + ra * 36;
            float part = pa * (p0 * grow[r0] + p1 * grow[r1] + p2 * grow[r2]
                             + p3 * grow[r3] + p4 * grow[r4]);
            if (kblk == 0) {
                const float* grow4 = gj + r4 * 36;
                part += p4 * (p0 * grow4[r0] + p1 * grow4[r1] + p2 * grow4[r2]
                            + p3 * grow4[r3] + p4 * grow4[r4]);
            }
            part += __shfl_xor(part, 16);
            part += __shfl_xor(part, 32);
            if (kblk == j) {
                float result = -1.f;
                if (w < clen) {
                    const float inv = __builtin_amdgcn_rcpf(sum);
                    const float a_ = 0.1f * num * inv;
                    const float den = __builtin_amdgcn_sqrtf(part) * inv + (-1e-8f);
                    result = a_ * __builtin_amdgcn_rcpf(den);
                }
                out[((size_t)(g * 4 + j) * N_CAP + c) * MAX_W + w] = result;
            }
        }
    }
}

extern "C" void kernel_launch(void* const* d_in, const int* in_sizes, int n_in,
                              void* d_out, int out_size, void* d_ws, size_t ws_size,
                              hipStream_t stream) {
    const float* imgs     = (const float*)d_in[0];
    const float* caps     = (const float*)d_in[1];
    const int*   img_lens = (const int*)d_in[2];
    const int*   cap_lens = (const int*)d_in[3];
    float* out = (float*)d_out;

    // d_ws layout
    float* G  = (float*)d_ws;                          // 128*1296*4 = 663552 B
    u8* imgsT = (u8*)d_ws + 663552;                    // 32*8*18432 = 4718592 B
    u8* capsT = imgsT + (size_t)32 * 8 * A_CHUNK;      // 32*8*16384 = 4194304 B

    hipFuncSetAttribute((const void*)vsc_mfma_kernel,
                        hipFuncAttributeMaxDynamicSharedMemorySize, LDS_BYTES);

    convert_kernel<<<2048, 256, 0, stream>>>(imgs, caps, imgsT, capsT);
    gram_i8_kernel<<<N_IMG, 256, 0, stream>>>(imgsT, G);
    vsc_mfma_kernel<<<1024, 256, LDS_BYTES, stream>>>(imgsT, capsT, img_lens, cap_lens, G, out);
}

// Round 18
// 77.650 us; speedup vs baseline: 1.0093x; 1.0093x over previous
//
#include <hip/hip_runtime.h>
#include <cmath>

#define N_IMG 128
#define MAX_R 36
#define N_CAP 128
#define MAX_W 32
#define DIM   512
#define NEGV  -1e30f

typedef unsigned short u16;
typedef unsigned int   u32;
typedef unsigned char  u8;
typedef __attribute__((ext_vector_type(4))) int i32x4;

#define NI_ELEMS (N_IMG * MAX_R * DIM)   // 2359296
#define NC_ELEMS (N_CAP * MAX_W * DIM)   // 2097152

// i8 chunk geometry (bytes)
#define A_CHUNK 18432   // imgs per (g,kb):   [h 144x64][l 144x64]
#define B_CHUNK 32768   // caps per (cg8,kb): [h 256x64][l 256x64]
// LDS: A double-buffered (2x18432) + B single (32768) = 69632 -> 2 blocks/CU.
// 8-wave blocks: grid 512 = EXACTLY 2/CU (no tail round); A staged once per
// 256 cap-cols -> total staged 285 -> 209 MB (R17 finding: time tracks
// staged bytes at ~4.3 TB/s across all configs).
#define LDS_BYTES 69632
#define A1_OFF 18432
#define B_OFF  36864

__device__ __forceinline__ void gload_lds16(const void* g, void* l) {
    __builtin_amdgcn_global_load_lds(
        (const __attribute__((address_space(1))) void*)g,
        (__attribute__((address_space(3))) void*)l, 16, 0, 0);
}

// ---------------------------------------------------------------------------
// Kernel 0: fp32 -> i16 -> (h,l) i8 split, pre-tiled + pre-swizzled.
// imgs: per (g, kb): rowT = imgRow % 144 (packed). caps: per (cg8 = c>>3, kb):
// row = (c&7)*32 + w (256 rows).
// ---------------------------------------------------------------------------
__global__ __launch_bounds__(256) void convert_kernel(const float* __restrict__ imgs,
                                                      const float* __restrict__ caps,
                                                      u8* __restrict__ imgsT,
                                                      u8* __restrict__ capsT) {
    const size_t ni4 = NI_ELEMS / 4;
    const size_t total4 = (NI_ELEMS + NC_ELEMS) / 4;
    const size_t stride = (size_t)gridDim.x * blockDim.x;
    for (size_t p = (size_t)blockIdx.x * blockDim.x + threadIdx.x; p < total4; p += stride) {
        const bool isImg = p < ni4;
        const float4 v = isImg ? ((const float4*)imgs)[p] : ((const float4*)caps)[p - ni4];
        const int q0 = (int)rintf(fminf(fmaxf(v.x * 4096.f, -32639.f), 32639.f));
        const int q1 = (int)rintf(fminf(fmaxf(v.y * 4096.f, -32639.f), 32639.f));
        const int q2 = (int)rintf(fminf(fmaxf(v.z * 4096.f, -32639.f), 32639.f));
        const int q3 = (int)rintf(fminf(fmaxf(v.w * 4096.f, -32639.f), 32639.f));
        const int h0 = (q0 + 128) >> 8, l0 = q0 - (h0 << 8);
        const int h1 = (q1 + 128) >> 8, l1 = q1 - (h1 << 8);
        const int h2 = (q2 + 128) >> 8, l2 = q2 - (h2 << 8);
        const int h3 = (q3 + 128) >> 8, l3 = q3 - (h3 << 8);
        const u32 hw = (u32)(h0 & 255) | ((u32)(h1 & 255) << 8) |
                       ((u32)(h2 & 255) << 16) | ((u32)(h3 & 255) << 24);
        const u32 lw = (u32)(l0 & 255) | ((u32)(l1 & 255) << 8) |
                       ((u32)(l2 & 255) << 16) | ((u32)(l3 & 255) << 24);
        if (isImg) {
            const int e = (int)(p * 4);
            const int imgRow = e >> 9, k = e & 511;
            const int g = imgRow / 144;
            const int rowT = imgRow - g * 144;
            const int kb = k >> 6, k6 = k & 63;
            const int blk = (k6 >> 4) ^ ((rowT >> 1) & 3);
            const size_t off = (size_t)(g * 8 + kb) * A_CHUNK + rowT * 64 + blk * 16 + (k6 & 15);
            *(u32*)(imgsT + off) = hw;
            *(u32*)(imgsT + off + 9216) = lw;
        } else {
            const int e = (int)((p - ni4) * 4);
            const int R = e >> 9, k = e & 511;
            const int c = R >> 5, w = R & 31;
            const int cg8 = c >> 3;
            const int row = (c & 7) * 32 + w;
            const int kb = k >> 6, k6 = k & 63;
            const int blk = (k6 >> 4) ^ ((row >> 1) & 3);
            const size_t off = (size_t)(cg8 * 8 + kb) * B_CHUNK + row * 64 + blk * 16 + (k6 & 15);
            *(u32*)(capsT + off) = hw;
            *(u32*)(capsT + off + 16384) = lw;
        }
    }
}

// ---------------------------------------------------------------------------
// Kernel A: per-image Gram via i8 MFMA from imgsT. Exact 3-acc fold.
// ---------------------------------------------------------------------------
__global__ __launch_bounds__(256) void gram_i8_kernel(const u8* __restrict__ imgsT,
                                                      float* __restrict__ G) {
    const int i  = blockIdx.x;
    const int gg = i >> 2;
    const int m  = i & 3;
    const int t = threadIdx.x;
    const int wid = t >> 6;
    const int lane = t & 63;
    const int l15 = lane & 15;
    const int kq = lane >> 4;

    __shared__ __align__(16) u8 sT[2][2][3072];   // [buf][h/l][48 rows x 64]

    const u8* base = imgsT + (size_t)gg * 8 * A_CHUNK + m * 36 * 64;

    auto stage = [&](int kb, int buf) {
        const u8* hsrc = base + (size_t)kb * A_CHUNK;
        {
            const int u = t;
            if (u < 144) gload_lds16(hsrc + u * 16, &sT[buf][0][u * 16]);
            else if (u < 288) gload_lds16(hsrc + 9216 + (u - 144) * 16, &sT[buf][1][(u - 144) * 16]);
        }
        if (t < 32) {
            const int u = 112 + t;
            gload_lds16(hsrc + 9216 + u * 16, &sT[buf][1][u * 16]);
        }
    };

    i32x4 aH[3], aC[3], aL[3];
    #pragma unroll
    for (int mt = 0; mt < 3; ++mt) {
        aH[mt] = (i32x4){0,0,0,0};
        aC[mt] = (i32x4){0,0,0,0};
        aL[mt] = (i32x4){0,0,0,0};
    }

    stage(0, 0);
    __syncthreads();

    const int m18 = 18 * m;
    for (int kb = 0; kb < 8; ++kb) {
        const int buf = kb & 1;
        if (kb < 7) stage(kb + 1, buf ^ 1);
        if (wid < 3) {
            const int brow = wid * 16 + l15;
            const int bblk = kq ^ ((m18 + (brow >> 1)) & 3);
            const i32x4 bh = *(const i32x4*)&sT[buf][0][brow * 64 + bblk * 16];
            const i32x4 bl = *(const i32x4*)&sT[buf][1][brow * 64 + bblk * 16];
            #pragma unroll
            for (int mt = 0; mt < 3; ++mt) {
                const int arow = mt * 16 + l15;
                const int ablk = kq ^ ((m18 + (arow >> 1)) & 3);
                const i32x4 ah = *(const i32x4*)&sT[buf][0][arow * 64 + ablk * 16];
                const i32x4 al = *(const i32x4*)&sT[buf][1][arow * 64 + ablk * 16];
                aH[mt] = __builtin_amdgcn_mfma_i32_16x16x64_i8(ah, bh, aH[mt], 0, 0, 0);
                aC[mt] = __builtin_amdgcn_mfma_i32_16x16x64_i8(ah, bl, aC[mt], 0, 0, 0);
                aC[mt] = __builtin_amdgcn_mfma_i32_16x16x64_i8(al, bh, aC[mt], 0, 0, 0);
                aL[mt] = __builtin_amdgcn_mfma_i32_16x16x64_i8(al, bl, aL[mt], 0, 0, 0);
            }
        }
        __syncthreads();
    }

    if (wid < 3) {
        const int col = wid * 16 + l15;
        if (col < 36) {
            #pragma unroll
            for (int mt = 0; mt < 3; ++mt) {
                #pragma unroll
                for (int e = 0; e < 4; ++e) {
                    const int row = mt * 16 + kq * 4 + e;
                    if (row < 36) {
                        const float g = (float)aH[mt][e] * (1.f / 256.f)
                                      + (float)aC[mt][e] * (1.f / 65536.f)
                                      + (float)aL[mt][e] * (1.f / 16777216.f);
                        G[(size_t)i * 1296 + row * 36 + col] = g;
                    }
                }
            }
        }
    }
}

// ---------------------------------------------------------------------------
// Kernel B: block = 4 images (144 M-rows) x 8 caps (256 N-cols), 8 WAVES
// (512 threads), wave tile 144x32 unchanged (same 36-acc reg footprint).
// Grid 512 = exactly 2 blocks/CU: no tail round, 16 waves/CU, A staged once
// per 256 cols (total staged 209 MB vs 285). One barrier/step; B wave-private.
// ---------------------------------------------------------------------------
__global__ __launch_bounds__(512, 2) void vsc_mfma_kernel(const u8* __restrict__ imgsT,
                                const u8* __restrict__ capsT,
                                const int* __restrict__ img_lens,
                                const int* __restrict__ cap_lens,
                                const float* __restrict__ G,
                                float* __restrict__ out) {
    extern __shared__ __align__(16) char smem[];
    const int bid = blockIdx.x;
    const int xcd = bid & 7;
    const int r_  = bid >> 3;          // 0..63
    const int g   = (r_ >> 4) * 8 + xcd;   // image tile 0..31 (4 imgs)
    const int cg8 = r_ & 15;               // cap group 0..15 (8 caps = 256 rows)
    const int t = threadIdx.x;
    const int wid = t >> 6;                // 0..7
    const int lane = t & 63;
    const int l15 = lane & 15;
    const int kblk = lane >> 4;            // also the epilogue quad index

    const u8* gA = imgsT + (size_t)g * 8 * A_CHUNK;
    const u8* gB = capsT + (size_t)cg8 * 8 * B_CHUNK;

    // A: 1152 16B-units split 8 ways (144/wave); B: own 32-row band (4 loads)
    auto stageA = [&](int kb, int abuf) {
        const u8* srcA = gA + (size_t)kb * A_CHUNK;
        char* dstA = smem + abuf * A1_OFF;
        const int ub = wid * 144;
        #pragma unroll
        for (int jj = 0; jj < 2; ++jj) {
            const int u = ub + jj * 64 + lane;
            gload_lds16(srcA + u * 16, dstA + u * 16);
        }
        if (lane < 16) {
            const int u = ub + 128 + lane;
            gload_lds16(srcA + u * 16, dstA + u * 16);
        }
    };
    auto stageB = [&](int kb) {
        const u8* srcB = gB + (size_t)kb * B_CHUNK;
        char* dstB = smem + B_OFF;
        #pragma unroll
        for (int jj = 0; jj < 2; ++jj) {
            const int u = wid * 128 + jj * 64 + lane;
            gload_lds16(srcB + u * 16, dstB + u * 16);                    // h
            gload_lds16(srcB + 16384 + u * 16, dstB + 16384 + u * 16);    // l
        }
    };

    i32x4 accH[9][2], accC[9][2];
    #pragma unroll
    for (int mt = 0; mt < 9; ++mt)
        #pragma unroll
        for (int nt = 0; nt < 2; ++nt) {
            accH[mt][nt] = (i32x4){0, 0, 0, 0};
            accC[mt][nt] = (i32x4){0, 0, 0, 0};
        }

    stageA(0, 0);
    stageB(0);

    const int blk16 = (kblk ^ ((l15 >> 1) & 3)) << 4;
    const int baseA = l15 * 64 + blk16;                // + mt*1024 ; h: +0, l: +9216
    const int baseB = (wid * 32 + l15) * 64 + blk16;   // + nt*1024 ; h: B_OFF, l: B_OFF+16384

    for (int kb = 0; kb < 8; ++kb) {
        // own stage(kb) loads landed (issued a full step ago; kb=0 pays once);
        // barrier publishes all waves' A slices.
        asm volatile("s_waitcnt vmcnt(0)" ::: "memory");
        __builtin_amdgcn_sched_barrier(0);
        __builtin_amdgcn_s_barrier();
        __builtin_amdgcn_sched_barrier(0);

        char* curA = smem + (size_t)(kb & 1) * A1_OFF;

        // A(kb+1) can issue now: its buffer's readers all passed the barrier.
        if (kb < 7) stageA(kb + 1, (kb + 1) & 1);

        // B -> registers (own band only); then own B region is dead.
        const i32x4 bh0 = *(const i32x4*)(smem + B_OFF + baseB);
        const i32x4 bl0 = *(const i32x4*)(smem + B_OFF + 16384 + baseB);
        const i32x4 bh1 = *(const i32x4*)(smem + B_OFF + baseB + 1024);
        const i32x4 bl1 = *(const i32x4*)(smem + B_OFF + 16384 + baseB + 1024);
        asm volatile("s_waitcnt lgkmcnt(0)" ::: "memory");
        __builtin_amdgcn_sched_barrier(0);

        if (kb < 7) stageB(kb + 1);

        __builtin_amdgcn_s_setprio(1);
        #pragma unroll
        for (int mt = 0; mt < 9; ++mt) {
            const i32x4 ah = *(const i32x4*)(curA + baseA + mt * 1024);
            const i32x4 al = *(const i32x4*)(curA + 9216 + baseA + mt * 1024);
            i32x4 lt0 = (i32x4){0, 0, 0, 0};
            i32x4 lt1 = (i32x4){0, 0, 0, 0};
            lt0 = __builtin_amdgcn_mfma_i32_16x16x64_i8(al, bl0, lt0, 0, 0, 0);
            lt1 = __builtin_amdgcn_mfma_i32_16x16x64_i8(al, bl1, lt1, 0, 0, 0);
            accH[mt][0] = __builtin_amdgcn_mfma_i32_16x16x64_i8(ah, bh0, accH[mt][0], 0, 0, 0);
            accH[mt][1] = __builtin_amdgcn_mfma_i32_16x16x64_i8(ah, bh1, accH[mt][1], 0, 0, 0);
            accC[mt][0] = __builtin_amdgcn_mfma_i32_16x16x64_i8(ah, bl0, accC[mt][0], 0, 0, 0);
            accC[mt][0] = __builtin_amdgcn_mfma_i32_16x16x64_i8(al, bh0, accC[mt][0], 0, 0, 0);
            accC[mt][1] = __builtin_amdgcn_mfma_i32_16x16x64_i8(ah, bl1, accC[mt][1], 0, 0, 0);
            accC[mt][1] = __builtin_amdgcn_mfma_i32_16x16x64_i8(al, bh1, accC[mt][1], 0, 0, 0);
            #pragma unroll
            for (int e = 0; e < 4; ++e) {
                accC[mt][0][e] += lt0[e] >> 8;   // truncation bias <= 1.2e-3 s-units
                accC[mt][1][e] += lt1[e] >> 8;
            }
        }
        __builtin_amdgcn_s_setprio(0);
    }

    __syncthreads();   // all LDS reads done; no outstanding staging

    // ---- stage Gram (4 imgs, fp32) into retired staging LDS
    float* sG = (float*)smem;
    {
        const float4* src = (const float4*)(G + (size_t)g * 4 * 1296);
        for (int idx = t; idx < 1296; idx += 512)
            ((float4*)sG)[idx] = src[idx];
    }
    __syncthreads();

    int ilen_[4];
    #pragma unroll
    for (int j = 0; j < 4; ++j) ilen_[j] = img_lens[g * 4 + j];

    #pragma unroll
    for (int nt = 0; nt < 2; ++nt) {
        const int col = wid * 32 + nt * 16 + l15;     // 0..255 cap-word col
        const int c = cg8 * 8 + (col >> 5);
        const int w = col & 31;
        const int clen = cap_lens[c];
        #pragma unroll
        for (int j = 0; j < 4; ++j) {
            const int mtb = (36 * j) >> 4;            // 0,2,4,6
            const int ilenj = ilen_[j];
            float vv[12];
            #pragma unroll
            for (int dm = 0; dm < 3; ++dm) {
                #pragma unroll
                for (int e = 0; e < 4; ++e) {
                    const int mt = mtb + dm;
                    const int r = mt * 16 + kblk * 4 + e;
                    const int rr = r - 36 * j;
                    const float sval = (float)accH[mt][nt][e] * (10.f / 256.f)
                                     + (float)accC[mt][nt][e] * (10.f / 65536.f);
                    vv[dm * 4 + e] = ((unsigned)rr < (unsigned)ilenj)
                        ? __uint_as_float((__float_as_uint(sval) & ~63u) | (u32)rr)
                        : NEGV;
                }
            }
            // 5x iterative global max over the 48 quad values
            float ta[5];
            #pragma unroll
            for (int s = 0; s < 5; ++s) {
                const float m0 = fmaxf(fmaxf(vv[0], vv[1]), vv[2]);
                const float m1 = fmaxf(fmaxf(vv[3], vv[4]), vv[5]);
                const float m2 = fmaxf(fmaxf(vv[6], vv[7]), vv[8]);
                const float m3 = fmaxf(fmaxf(vv[9], vv[10]), vv[11]);
                float q = fmaxf(fmaxf(fmaxf(m0, m1), m2), m3);
                q = fmaxf(q, __shfl_xor(q, 16));
                q = fmaxf(q, __shfl_xor(q, 32));
                ta[s] = q;
                if (s < 4) {
                    #pragma unroll
                    for (int k = 0; k < 12; ++k)
                        vv[k] = (vv[k] == q) ? NEGV : vv[k];
                }
            }
            // softmax over the 5
            const float m = ta[0];
            const float p0 = 1.f;
            const float p1 = __expf(ta[1] - m);
            const float p2 = __expf(ta[2] - m);
            const float p3 = __expf(ta[3] - m);
            const float p4 = __expf(ta[4] - m);
            const float sum = p0 + p1 + p2 + p3 + p4;
            const float num = p0 * ta[0] + p1 * ta[1] + p2 * ta[2] + p3 * ta[3] + p4 * ta[4];
            const int r0 = __float_as_uint(ta[0]) & 63;
            const int r1 = __float_as_uint(ta[1]) & 63;
            const int r2 = __float_as_uint(ta[2]) & 63;
            const int r3 = __float_as_uint(ta[3]) & 63;
            const int r4 = __float_as_uint(ta[4]) & 63;
            const float* gj = sG + j * 1296;
            const float pa = (kblk == 0) ? p0 : (kblk == 1) ? p1 : (kblk == 2) ? p2 : p3;
            const int   ra = (kblk == 0) ? r0 : (kblk == 1) ? r1 : (kblk == 2) ? r2 : r3;
            const float* grow = gj + ra * 36;
            float part = pa * (p0 * grow[r0] + p1 * grow[r1] + p2 * grow[r2]
                             + p3 * grow[r3] + p4 * grow[r4]);
            if (kblk == 0) {
                const float* grow4 = gj + r4 * 36;
                part += p4 * (p0 * grow4[r0] + p1 * grow4[r1] + p2 * grow4[r2]
                            + p3 * grow4[r3] + p4 * grow4[r4]);
            }
            part += __shfl_xor(part, 16);
            part += __shfl_xor(part, 32);
            if (kblk == j) {
                float result = -1.f;
                if (w < clen) {
                    const float inv = __builtin_amdgcn_rcpf(sum);
                    const float a_ = 0.1f * num * inv;
                    const float den = __builtin_amdgcn_sqrtf(part) * inv + (-1e-8f);
                    result = a_ * __builtin_amdgcn_rcpf(den);
                }
                out[((size_t)(g * 4 + j) * N_CAP + c) * MAX_W + w] = result;
            }
        }
    }
}

extern "C" void kernel_launch(void* const* d_in, const int* in_sizes, int n_in,
                              void* d_out, int out_size, void* d_ws, size_t ws_size,
                              hipStream_t stream) {
    const float* imgs     = (const float*)d_in[0];
    const float* caps     = (const float*)d_in[1];
    const int*   img_lens = (const int*)d_in[2];
    const int*   cap_lens = (const int*)d_in[3];
    float* out = (float*)d_out;

    // d_ws layout
    float* G  = (float*)d_ws;                          // 128*1296*4 = 663552 B
    u8* imgsT = (u8*)d_ws + 663552;                    // 32*8*18432 = 4718592 B
    u8* capsT = imgsT + (size_t)32 * 8 * A_CHUNK;      // 16*8*32768 = 4194304 B

    hipFuncSetAttribute((const void*)vsc_mfma_kernel,
                        hipFuncAttributeMaxDynamicSharedMemorySize, LDS_BYTES);

    convert_kernel<<<2048, 256, 0, stream>>>(imgs, caps, imgsT, capsT);
    gram_i8_kernel<<<N_IMG, 256, 0, stream>>>(imgsT, G);
    vsc_mfma_kernel<<<512, 512, LDS_BYTES, stream>>>(imgsT, capsT, img_lens, cap_lens, G, out);
}

// Round 19
// 76.801 us; speedup vs baseline: 1.0205x; 1.0110x over previous
//
#include <hip/hip_runtime.h>
#include <cmath>

#define N_IMG 128
#define MAX_R 36
#define N_CAP 128
#define MAX_W 32
#define DIM   512
#define NEGV  -1e30f

typedef unsigned short u16;
typedef unsigned int   u32;
typedef unsigned char  u8;
typedef __attribute__((ext_vector_type(4))) int i32x4;

#define NI_ELEMS (N_IMG * MAX_R * DIM)   // 2359296
#define NC_ELEMS (N_CAP * MAX_W * DIM)   // 2097152
#define TOTAL4   ((NI_ELEMS + NC_ELEMS) / 4)   // 1114112 = 4352 * 256

// i8 chunk geometry (bytes)
#define A_CHUNK 18432   // imgs per (g,kb):  [h 144x64][l 144x64]
#define B_CHUNK 16384   // caps per (cg,kb): [h 128x64][l 128x64]
// LDS: A double-buffered (2x18432) + B SINGLE-buffered (16384) = 53248
// -> 3 blocks/CU. launch_bounds(256,2): 128 VGPR, no spill.
// R18 lesson: vsc time (63-66us) is invariant to waves/CU (8/12/16), staged
// bytes (285/209MB), VALU (-10%), barriers, schedule -> per-wave equilibrium.
// This config (R16 bench) is the best measured: 63.2us.
#define LDS_BYTES 53248
#define A1_OFF 18432
#define B_OFF  36864

__device__ __forceinline__ void gload_lds16(const void* g, void* l) {
    __builtin_amdgcn_global_load_lds(
        (const __attribute__((address_space(1))) void*)g,
        (__attribute__((address_space(3))) void*)l, 16, 0, 0);
}

// ---------------------------------------------------------------------------
// Kernel 0: fp32 -> i16 -> (h,l) i8 split, pre-tiled + pre-swizzled.
// Exact-cover grid: 4352 blocks x 256 threads = 1 float4 per thread.
// ---------------------------------------------------------------------------
__global__ __launch_bounds__(256) void convert_kernel(const float* __restrict__ imgs,
                                                      const float* __restrict__ caps,
                                                      u8* __restrict__ imgsT,
                                                      u8* __restrict__ capsT) {
    const size_t ni4 = NI_ELEMS / 4;
    const size_t p = (size_t)blockIdx.x * blockDim.x + threadIdx.x;
    if (p >= TOTAL4) return;
    const bool isImg = p < ni4;
    const float4 v = isImg ? ((const float4*)imgs)[p] : ((const float4*)caps)[p - ni4];
    const int q0 = (int)rintf(fminf(fmaxf(v.x * 4096.f, -32639.f), 32639.f));
    const int q1 = (int)rintf(fminf(fmaxf(v.y * 4096.f, -32639.f), 32639.f));
    const int q2 = (int)rintf(fminf(fmaxf(v.z * 4096.f, -32639.f), 32639.f));
    const int q3 = (int)rintf(fminf(fmaxf(v.w * 4096.f, -32639.f), 32639.f));
    const int h0 = (q0 + 128) >> 8, l0 = q0 - (h0 << 8);
    const int h1 = (q1 + 128) >> 8, l1 = q1 - (h1 << 8);
    const int h2 = (q2 + 128) >> 8, l2 = q2 - (h2 << 8);
    const int h3 = (q3 + 128) >> 8, l3 = q3 - (h3 << 8);
    const u32 hw = (u32)(h0 & 255) | ((u32)(h1 & 255) << 8) |
                   ((u32)(h2 & 255) << 16) | ((u32)(h3 & 255) << 24);
    const u32 lw = (u32)(l0 & 255) | ((u32)(l1 & 255) << 8) |
                   ((u32)(l2 & 255) << 16) | ((u32)(l3 & 255) << 24);
    if (isImg) {
        const int e = (int)(p * 4);
        const int imgRow = e >> 9, k = e & 511;
        const int g = imgRow / 144;
        const int rowT = imgRow - g * 144;
        const int kb = k >> 6, k6 = k & 63;
        const int blk = (k6 >> 4) ^ ((rowT >> 1) & 3);
        const size_t off = (size_t)(g * 8 + kb) * A_CHUNK + rowT * 64 + blk * 16 + (k6 & 15);
        *(u32*)(imgsT + off) = hw;
        *(u32*)(imgsT + off + 9216) = lw;
    } else {
        const int e = (int)((p - ni4) * 4);
        const int R = e >> 9, k = e & 511;
        const int cg = R >> 7, row = R & 127;
        const int kb = k >> 6, k6 = k & 63;
        const int blk = (k6 >> 4) ^ ((row >> 1) & 3);
        const size_t off = (size_t)(cg * 8 + kb) * B_CHUNK + row * 64 + blk * 16 + (k6 & 15);
        *(u32*)(capsT + off) = hw;
        *(u32*)(capsT + off + 8192) = lw;
    }
}

// ---------------------------------------------------------------------------
// Kernel A: per-image Gram via i8 MFMA from imgsT. Exact 3-acc fold.
// ---------------------------------------------------------------------------
__global__ __launch_bounds__(256) void gram_i8_kernel(const u8* __restrict__ imgsT,
                                                      float* __restrict__ G) {
    const int i  = blockIdx.x;
    const int gg = i >> 2;
    const int m  = i & 3;
    const int t = threadIdx.x;
    const int wid = t >> 6;
    const int lane = t & 63;
    const int l15 = lane & 15;
    const int kq = lane >> 4;

    __shared__ __align__(16) u8 sT[2][2][3072];   // [buf][h/l][48 rows x 64]

    const u8* base = imgsT + (size_t)gg * 8 * A_CHUNK + m * 36 * 64;

    auto stage = [&](int kb, int buf) {
        const u8* hsrc = base + (size_t)kb * A_CHUNK;
        {
            const int u = t;
            if (u < 144) gload_lds16(hsrc + u * 16, &sT[buf][0][u * 16]);
            else if (u < 288) gload_lds16(hsrc + 9216 + (u - 144) * 16, &sT[buf][1][(u - 144) * 16]);
        }
        if (t < 32) {
            const int u = 112 + t;
            gload_lds16(hsrc + 9216 + u * 16, &sT[buf][1][u * 16]);
        }
    };

    i32x4 aH[3], aC[3], aL[3];
    #pragma unroll
    for (int mt = 0; mt < 3; ++mt) {
        aH[mt] = (i32x4){0,0,0,0};
        aC[mt] = (i32x4){0,0,0,0};
        aL[mt] = (i32x4){0,0,0,0};
    }

    stage(0, 0);
    __syncthreads();

    const int m18 = 18 * m;
    for (int kb = 0; kb < 8; ++kb) {
        const int buf = kb & 1;
        if (kb < 7) stage(kb + 1, buf ^ 1);
        if (wid < 3) {
            const int brow = wid * 16 + l15;
            const int bblk = kq ^ ((m18 + (brow >> 1)) & 3);
            const i32x4 bh = *(const i32x4*)&sT[buf][0][brow * 64 + bblk * 16];
            const i32x4 bl = *(const i32x4*)&sT[buf][1][brow * 64 + bblk * 16];
            #pragma unroll
            for (int mt = 0; mt < 3; ++mt) {
                const int arow = mt * 16 + l15;
                const int ablk = kq ^ ((m18 + (arow >> 1)) & 3);
                const i32x4 ah = *(const i32x4*)&sT[buf][0][arow * 64 + ablk * 16];
                const i32x4 al = *(const i32x4*)&sT[buf][1][arow * 64 + ablk * 16];
                aH[mt] = __builtin_amdgcn_mfma_i32_16x16x64_i8(ah, bh, aH[mt], 0, 0, 0);
                aC[mt] = __builtin_amdgcn_mfma_i32_16x16x64_i8(ah, bl, aC[mt], 0, 0, 0);
                aC[mt] = __builtin_amdgcn_mfma_i32_16x16x64_i8(al, bh, aC[mt], 0, 0, 0);
                aL[mt] = __builtin_amdgcn_mfma_i32_16x16x64_i8(al, bl, aL[mt], 0, 0, 0);
            }
        }
        __syncthreads();
    }

    if (wid < 3) {
        const int col = wid * 16 + l15;
        if (col < 36) {
            #pragma unroll
            for (int mt = 0; mt < 3; ++mt) {
                #pragma unroll
                for (int e = 0; e < 4; ++e) {
                    const int row = mt * 16 + kq * 4 + e;
                    if (row < 36) {
                        const float g = (float)aH[mt][e] * (1.f / 256.f)
                                      + (float)aC[mt][e] * (1.f / 65536.f)
                                      + (float)aL[mt][e] * (1.f / 16777216.f);
                        G[(size_t)i * 1296 + row * 36 + col] = g;
                    }
                }
            }
        }
    }
}

// ---------------------------------------------------------------------------
// Kernel B: block = 4 images (144 M-rows) x 4 caps (128 N-cols), 4 waves.
// i8 exact split MFMA. One barrier/step; B wave-private single-buffer.
// This is the best-measured config (63.2us, R16 bench) reinstated verbatim.
// ---------------------------------------------------------------------------
__global__ __launch_bounds__(256, 2) void vsc_mfma_kernel(const u8* __restrict__ imgsT,
                                const u8* __restrict__ capsT,
                                const int* __restrict__ img_lens,
                                const int* __restrict__ cap_lens,
                                const float* __restrict__ G,
                                float* __restrict__ out) {
    extern __shared__ __align__(16) char smem[];
    const int bid = blockIdx.x;
    const int xcd = bid & 7;
    const int r_  = bid >> 3;
    const int g   = (r_ >> 5) * 8 + xcd;   // image tile 0..31 (4 imgs)
    const int cg  = r_ & 31;               // cap group 0..31 (4 caps = 128 rows)
    const int t = threadIdx.x;
    const int wid = t >> 6;                // 0..3
    const int lane = t & 63;
    const int l15 = lane & 15;
    const int kblk = lane >> 4;            // also the epilogue quad index

    const u8* gA = imgsT + (size_t)g * 8 * A_CHUNK;
    const u8* gB = capsT + (size_t)cg * 8 * B_CHUNK;

    // Each wave stages its QUARTER of A into abuf + its OWN 32-row B band.
    auto stage = [&](int kb, int abuf) {
        const u8* srcA = gA + (size_t)kb * A_CHUNK;
        char* dstA = smem + abuf * A1_OFF;
        {
            const int ub = wid * 288;
            #pragma unroll
            for (int jj = 0; jj < 4; ++jj) {
                const int u = ub + jj * 64 + lane;
                gload_lds16(srcA + u * 16, dstA + u * 16);
            }
            if (lane < 32) {
                const int u = ub + 256 + lane;
                gload_lds16(srcA + u * 16, dstA + u * 16);
            }
        }
        const u8* srcB = gB + (size_t)kb * B_CHUNK;
        char* dstB = smem + B_OFF;
        #pragma unroll
        for (int jj = 0; jj < 2; ++jj) {
            const int u = wid * 128 + jj * 64 + lane;
            gload_lds16(srcB + u * 16, dstB + u * 16);                  // h
            gload_lds16(srcB + 8192 + u * 16, dstB + 8192 + u * 16);    // l
        }
    };

    i32x4 accH[9][2], accC[9][2];
    #pragma unroll
    for (int mt = 0; mt < 9; ++mt)
        #pragma unroll
        for (int nt = 0; nt < 2; ++nt) {
            accH[mt][nt] = (i32x4){0, 0, 0, 0};
            accC[mt][nt] = (i32x4){0, 0, 0, 0};
        }

    stage(0, 0);

    const int blk16 = (kblk ^ ((l15 >> 1) & 3)) << 4;
    const int baseA = l15 * 64 + blk16;                // + mt*1024 ; h: +0, l: +9216
    const int baseB = (wid * 32 + l15) * 64 + blk16;   // + nt*1024 ; h: B_OFF, l: B_OFF+8192

    for (int kb = 0; kb < 8; ++kb) {
        asm volatile("s_waitcnt vmcnt(0)" ::: "memory");
        __builtin_amdgcn_sched_barrier(0);
        __builtin_amdgcn_s_barrier();
        __builtin_amdgcn_sched_barrier(0);

        char* curA = smem + (size_t)(kb & 1) * A1_OFF;

        // B -> registers (own band only); then own B region is dead.
        const i32x4 bh0 = *(const i32x4*)(smem + B_OFF + baseB);
        const i32x4 bl0 = *(const i32x4*)(smem + B_OFF + 8192 + baseB);
        const i32x4 bh1 = *(const i32x4*)(smem + B_OFF + baseB + 1024);
        const i32x4 bl1 = *(const i32x4*)(smem + B_OFF + 8192 + baseB + 1024);
        asm volatile("s_waitcnt lgkmcnt(0)" ::: "memory");
        __builtin_amdgcn_sched_barrier(0);

        if (kb < 7) stage(kb + 1, (kb + 1) & 1);

        __builtin_amdgcn_s_setprio(1);
        #pragma unroll
        for (int mt = 0; mt < 9; ++mt) {
            const i32x4 ah = *(const i32x4*)(curA + baseA + mt * 1024);
            const i32x4 al = *(const i32x4*)(curA + 9216 + baseA + mt * 1024);
            i32x4 lt0 = (i32x4){0, 0, 0, 0};
            i32x4 lt1 = (i32x4){0, 0, 0, 0};
            lt0 = __builtin_amdgcn_mfma_i32_16x16x64_i8(al, bl0, lt0, 0, 0, 0);
            lt1 = __builtin_amdgcn_mfma_i32_16x16x64_i8(al, bl1, lt1, 0, 0, 0);
            accH[mt][0] = __builtin_amdgcn_mfma_i32_16x16x64_i8(ah, bh0, accH[mt][0], 0, 0, 0);
            accH[mt][1] = __builtin_amdgcn_mfma_i32_16x16x64_i8(ah, bh1, accH[mt][1], 0, 0, 0);
            accC[mt][0] = __builtin_amdgcn_mfma_i32_16x16x64_i8(ah, bl0, accC[mt][0], 0, 0, 0);
            accC[mt][0] = __builtin_amdgcn_mfma_i32_16x16x64_i8(al, bh0, accC[mt][0], 0, 0, 0);
            accC[mt][1] = __builtin_amdgcn_mfma_i32_16x16x64_i8(ah, bl1, accC[mt][1], 0, 0, 0);
            accC[mt][1] = __builtin_amdgcn_mfma_i32_16x16x64_i8(al, bh1, accC[mt][1], 0, 0, 0);
            #pragma unroll
            for (int e = 0; e < 4; ++e) {
                accC[mt][0][e] += lt0[e] >> 8;   // truncation bias <= 1.2e-3 s-units
                accC[mt][1][e] += lt1[e] >> 8;
            }
        }
        __builtin_amdgcn_s_setprio(0);
    }

    __syncthreads();   // all LDS reads done; no outstanding staging

    // ---- stage Gram (4 imgs, fp32) into retired staging LDS
    float* sG = (float*)smem;
    {
        const float4* src = (const float4*)(G + (size_t)g * 4 * 1296);
        for (int idx = t; idx < 1296; idx += 256)
            ((float4*)sG)[idx] = src[idx];
    }
    __syncthreads();

    int ilen_[4];
    #pragma unroll
    for (int j = 0; j < 4; ++j) ilen_[j] = img_lens[g * 4 + j];

    #pragma unroll
    for (int nt = 0; nt < 2; ++nt) {
        const int col = wid * 32 + nt * 16 + l15;     // 0..127 cap-word col
        const int c = cg * 4 + (col >> 5);
        const int w = col & 31;
        const int clen = cap_lens[c];
        #pragma unroll
        for (int j = 0; j < 4; ++j) {
            const int mtb = (36 * j) >> 4;            // 0,2,4,6
            const int ilenj = ilen_[j];
            float tv0 = NEGV, tv1 = NEGV, tv2 = NEGV, tv3 = NEGV, tv4 = NEGV;
            #pragma unroll
            for (int dm = 0; dm < 3; ++dm) {
                #pragma unroll
                for (int e = 0; e < 4; ++e) {
                    const int mt = mtb + dm;
                    const int r = mt * 16 + kblk * 4 + e;
                    const int rr = r - 36 * j;
                    const float sval = (float)accH[mt][nt][e] * (10.f / 256.f)
                                     + (float)accC[mt][nt][e] * (10.f / 65536.f);
                    float v = NEGV;
                    if ((unsigned)rr < (unsigned)ilenj)
                        v = __uint_as_float((__float_as_uint(sval) & ~63u) | (u32)rr);
                    const bool c0 = v > tv0, c1 = v > tv1, c2 = v > tv2, c3 = v > tv3, c4 = v > tv4;
                    const float n4 = c4 ? (c3 ? tv3 : v) : tv4;
                    const float n3 = c3 ? (c2 ? tv2 : v) : tv3;
                    const float n2 = c2 ? (c1 ? tv1 : v) : tv2;
                    const float n1 = c1 ? (c0 ? tv0 : v) : tv1;
                    const float n0 = c0 ? v : tv0;
                    tv0 = n0; tv1 = n1; tv2 = n2; tv3 = n3; tv4 = n4;
                }
            }
            float ta[5] = {tv0, tv1, tv2, tv3, tv4};
            #pragma unroll
            for (int st = 0; st < 2; ++st) {
                const int dx = 16 << st;
                float tb[5];
                #pragma unroll
                for (int s = 0; s < 5; ++s) tb[s] = __shfl_xor(ta[s], dx);
                float na[5];
                #pragma unroll
                for (int k = 0; k < 5; ++k) {
                    float best = fmaxf(ta[k], tb[k]);
                    #pragma unroll
                    for (int i2 = 1; i2 <= k; ++i2)
                        best = fmaxf(best, fminf(ta[i2 - 1], tb[k - i2]));
                    na[k] = best;
                }
                #pragma unroll
                for (int s = 0; s < 5; ++s) ta[s] = na[s];
            }
            const float m = ta[0];
            const float p0 = 1.f;
            const float p1 = __expf(ta[1] - m);
            const float p2 = __expf(ta[2] - m);
            const float p3 = __expf(ta[3] - m);
            const float p4 = __expf(ta[4] - m);
            const float sum = p0 + p1 + p2 + p3 + p4;
            const float num = p0 * ta[0] + p1 * ta[1] + p2 * ta[2] + p3 * ta[3] + p4 * ta[4];
            const int r0 = __float_as_uint(ta[0]) & 63;
            const int r1 = __float_as_uint(ta[1]) & 63;
            const int r2 = __float_as_uint(ta[2]) & 63;
            const int r3 = __float_as_uint(ta[3]) & 63;
            const int r4 = __float_as_uint(ta[4]) & 63;
            const float* gj = sG + j * 1296;
            const float pa = (kblk == 0) ? p0 : (kblk == 1) ? p1 : (kblk == 2) ? p2 : p3;
            const int   ra = (kblk == 0) ? r0 : (kblk == 1) ? r1 : (kblk == 2) ? r2 : r3;
            const float* grow = gj + ra * 36;
            float part = pa * (p0 * grow[r0] + p1 * grow[r1] + p2 * grow[r2]
                             + p3 * grow[r3] + p4 * grow[r4]);
            if (kblk == 0) {
                const float* grow4 = gj + r4 * 36;
                part += p4 * (p0 * grow4[r0] + p1 * grow4[r1] + p2 * grow4[r2]
                            + p3 * grow4[r3] + p4 * grow4[r4]);
            }
            part += __shfl_xor(part, 16);
            part += __shfl_xor(part, 32);
            if (kblk == j) {
                float result = -1.f;
                if (w < clen) {
                    const float inv = __builtin_amdgcn_rcpf(sum);
                    const float a_ = 0.1f * num * inv;
                    const float den = __builtin_amdgcn_sqrtf(part) * inv + (-1e-8f);
                    result = a_ * __builtin_amdgcn_rcpf(den);
                }
                out[((size_t)(g * 4 + j) * N_CAP + c) * MAX_W + w] = result;
            }
        }
    }
}

extern "C" void kernel_launch(void* const* d_in, const int* in_sizes, int n_in,
                              void* d_out, int out_size, void* d_ws, size_t ws_size,
                              hipStream_t stream) {
    const float* imgs     = (const float*)d_in[0];
    const float* caps     = (const float*)d_in[1];
    const int*   img_lens = (const int*)d_in[2];
    const int*   cap_lens = (const int*)d_in[3];
    float* out = (float*)d_out;

    // d_ws layout
    float* G  = (float*)d_ws;                          // 128*1296*4 = 663552 B
    u8* imgsT = (u8*)d_ws + 663552;                    // 32*8*18432 = 4718592 B
    u8* capsT = imgsT + (size_t)32 * 8 * A_CHUNK;      // 32*8*16384 = 4194304 B

    hipFuncSetAttribute((const void*)vsc_mfma_kernel,
                        hipFuncAttributeMaxDynamicSharedMemorySize, LDS_BYTES);

    convert_kernel<<<4352, 256, 0, stream>>>(imgs, caps, imgsT, capsT);
    gram_i8_kernel<<<N_IMG, 256, 0, stream>>>(imgsT, G);
    vsc_mfma_kernel<<<1024, 256, LDS_BYTES, stream>>>(imgsT, capsT, img_lens, cap_lens, G, out);
}

// Round 21
// 76.310 us; speedup vs baseline: 1.0271x; 1.0064x over previous
//
#include <hip/hip_runtime.h>
#include <cmath>

#define N_IMG 128
#define MAX_R 36
#define N_CAP 128
#define MAX_W 32
#define DIM   512
#define NEGV  -1e30f

typedef unsigned short u16;
typedef unsigned int   u32;
typedef unsigned char  u8;
typedef __attribute__((ext_vector_type(4))) int i32x4;

#define NI_ELEMS (N_IMG * MAX_R * DIM)   // 2359296
#define NC_ELEMS (N_CAP * MAX_W * DIM)   // 2097152
#define TOTAL4   ((NI_ELEMS + NC_ELEMS) / 4)   // 1114112 = 4352 * 256

// i8 chunk geometry (bytes)
#define A_CHUNK 18432   // imgs per (g,kb):  [h 144x64][l 144x64]
#define B_CHUNK 16384   // caps per (cg,kb): [h 128x64][l 128x64]
// LDS: A double-buffered (2x18432) + B SINGLE-buffered (16384) = 53248
// -> 3 blocks/CU. launch_bounds(256,2): 128 VGPR, no spill.
// R20 lesson: cooperative fusion (grid.sync) is UNSAFE here — reader-side
// per-XCD L2 staleness for producer data (guide G16); separate dispatches
// provide the needed system-scope flush/invalidate. This file is the proven
// R19 config (76.8us total, vsc 63.1us).
#define LDS_BYTES 53248
#define A1_OFF 18432
#define B_OFF  36864

__device__ __forceinline__ void gload_lds16(const void* g, void* l) {
    __builtin_amdgcn_global_load_lds(
        (const __attribute__((address_space(1))) void*)g,
        (__attribute__((address_space(3))) void*)l, 16, 0, 0);
}

// ---------------------------------------------------------------------------
// Kernel 0: fp32 -> i16 -> (h,l) i8 split, pre-tiled + pre-swizzled.
// Exact-cover grid: 4352 blocks x 256 threads = 1 float4 per thread.
// ---------------------------------------------------------------------------
__global__ __launch_bounds__(256) void convert_kernel(const float* __restrict__ imgs,
                                                      const float* __restrict__ caps,
                                                      u8* __restrict__ imgsT,
                                                      u8* __restrict__ capsT) {
    const size_t ni4 = NI_ELEMS / 4;
    const size_t p = (size_t)blockIdx.x * blockDim.x + threadIdx.x;
    if (p >= TOTAL4) return;
    const bool isImg = p < ni4;
    const float4 v = isImg ? ((const float4*)imgs)[p] : ((const float4*)caps)[p - ni4];
    const int q0 = (int)rintf(fminf(fmaxf(v.x * 4096.f, -32639.f), 32639.f));
    const int q1 = (int)rintf(fminf(fmaxf(v.y * 4096.f, -32639.f), 32639.f));
    const int q2 = (int)rintf(fminf(fmaxf(v.z * 4096.f, -32639.f), 32639.f));
    const int q3 = (int)rintf(fminf(fmaxf(v.w * 4096.f, -32639.f), 32639.f));
    const int h0 = (q0 + 128) >> 8, l0 = q0 - (h0 << 8);
    const int h1 = (q1 + 128) >> 8, l1 = q1 - (h1 << 8);
    const int h2 = (q2 + 128) >> 8, l2 = q2 - (h2 << 8);
    const int h3 = (q3 + 128) >> 8, l3 = q3 - (h3 << 8);
    const u32 hw = (u32)(h0 & 255) | ((u32)(h1 & 255) << 8) |
                   ((u32)(h2 & 255) << 16) | ((u32)(h3 & 255) << 24);
    const u32 lw = (u32)(l0 & 255) | ((u32)(l1 & 255) << 8) |
                   ((u32)(l2 & 255) << 16) | ((u32)(l3 & 255) << 24);
    if (isImg) {
        const int e = (int)(p * 4);
        const int imgRow = e >> 9, k = e & 511;
        const int g = imgRow / 144;
        const int rowT = imgRow - g * 144;
        const int kb = k >> 6, k6 = k & 63;
        const int blk = (k6 >> 4) ^ ((rowT >> 1) & 3);
        const size_t off = (size_t)(g * 8 + kb) * A_CHUNK + rowT * 64 + blk * 16 + (k6 & 15);
        *(u32*)(imgsT + off) = hw;
        *(u32*)(imgsT + off + 9216) = lw;
    } else {
        const int e = (int)((p - ni4) * 4);
        const int R = e >> 9, k = e & 511;
        const int cg = R >> 7, row = R & 127;
        const int kb = k >> 6, k6 = k & 63;
        const int blk = (k6 >> 4) ^ ((row >> 1) & 3);
        const size_t off = (size_t)(cg * 8 + kb) * B_CHUNK + row * 64 + blk * 16 + (k6 & 15);
        *(u32*)(capsT + off) = hw;
        *(u32*)(capsT + off + 8192) = lw;
    }
}

// ---------------------------------------------------------------------------
// Kernel A: per-image Gram via i8 MFMA from imgsT. Exact 3-acc fold.
// ---------------------------------------------------------------------------
__global__ __launch_bounds__(256) void gram_i8_kernel(const u8* __restrict__ imgsT,
                                                      float* __restrict__ G) {
    const int i  = blockIdx.x;
    const int gg = i >> 2;
    const int m  = i & 3;
    const int t = threadIdx.x;
    const int wid = t >> 6;
    const int lane = t & 63;
    const int l15 = lane & 15;
    const int kq = lane >> 4;

    __shared__ __align__(16) u8 sT[2][2][3072];   // [buf][h/l][48 rows x 64]

    const u8* base = imgsT + (size_t)gg * 8 * A_CHUNK + m * 36 * 64;

    auto stage = [&](int kb, int buf) {
        const u8* hsrc = base + (size_t)kb * A_CHUNK;
        {
            const int u = t;
            if (u < 144) gload_lds16(hsrc + u * 16, &sT[buf][0][u * 16]);
            else if (u < 288) gload_lds16(hsrc + 9216 + (u - 144) * 16, &sT[buf][1][(u - 144) * 16]);
        }
        if (t < 32) {
            const int u = 112 + t;
            gload_lds16(hsrc + 9216 + u * 16, &sT[buf][1][u * 16]);
        }
    };

    i32x4 aH[3], aC[3], aL[3];
    #pragma unroll
    for (int mt = 0; mt < 3; ++mt) {
        aH[mt] = (i32x4){0,0,0,0};
        aC[mt] = (i32x4){0,0,0,0};
        aL[mt] = (i32x4){0,0,0,0};
    }

    stage(0, 0);
    __syncthreads();

    const int m18 = 18 * m;
    for (int kb = 0; kb < 8; ++kb) {
        const int buf = kb & 1;
        if (kb < 7) stage(kb + 1, buf ^ 1);
        if (wid < 3) {
            const int brow = wid * 16 + l15;
            const int bblk = kq ^ ((m18 + (brow >> 1)) & 3);
            const i32x4 bh = *(const i32x4*)&sT[buf][0][brow * 64 + bblk * 16];
            const i32x4 bl = *(const i32x4*)&sT[buf][1][brow * 64 + bblk * 16];
            #pragma unroll
            for (int mt = 0; mt < 3; ++mt) {
                const int arow = mt * 16 + l15;
                const int ablk = kq ^ ((m18 + (arow >> 1)) & 3);
                const i32x4 ah = *(const i32x4*)&sT[buf][0][arow * 64 + ablk * 16];
                const i32x4 al = *(const i32x4*)&sT[buf][1][arow * 64 + ablk * 16];
                aH[mt] = __builtin_amdgcn_mfma_i32_16x16x64_i8(ah, bh, aH[mt], 0, 0, 0);
                aC[mt] = __builtin_amdgcn_mfma_i32_16x16x64_i8(ah, bl, aC[mt], 0, 0, 0);
                aC[mt] = __builtin_amdgcn_mfma_i32_16x16x64_i8(al, bh, aC[mt], 0, 0, 0);
                aL[mt] = __builtin_amdgcn_mfma_i32_16x16x64_i8(al, bl, aL[mt], 0, 0, 0);
            }
        }
        __syncthreads();
    }

    if (wid < 3) {
        const int col = wid * 16 + l15;
        if (col < 36) {
            #pragma unroll
            for (int mt = 0; mt < 3; ++mt) {
                #pragma unroll
                for (int e = 0; e < 4; ++e) {
                    const int row = mt * 16 + kq * 4 + e;
                    if (row < 36) {
                        const float g = (float)aH[mt][e] * (1.f / 256.f)
                                      + (float)aC[mt][e] * (1.f / 65536.f)
                                      + (float)aL[mt][e] * (1.f / 16777216.f);
                        G[(size_t)i * 1296 + row * 36 + col] = g;
                    }
                }
            }
        }
    }
}

// ---------------------------------------------------------------------------
// Kernel B: block = 4 images (144 M-rows) x 4 caps (128 N-cols), 4 waves.
// i8 exact split MFMA. One barrier/step; B wave-private single-buffer.
// Best-measured config (63.1-63.2us) — pinned across 7 orthogonal levers.
// ---------------------------------------------------------------------------
__global__ __launch_bounds__(256, 2) void vsc_mfma_kernel(const u8* __restrict__ imgsT,
                                const u8* __restrict__ capsT,
                                const int* __restrict__ img_lens,
                                const int* __restrict__ cap_lens,
                                const float* __restrict__ G,
                                float* __restrict__ out) {
    extern __shared__ __align__(16) char smem[];
    const int bid = blockIdx.x;
    const int xcd = bid & 7;
    const int r_  = bid >> 3;
    const int g   = (r_ >> 5) * 8 + xcd;   // image tile 0..31 (4 imgs)
    const int cg  = r_ & 31;               // cap group 0..31 (4 caps = 128 rows)
    const int t = threadIdx.x;
    const int wid = t >> 6;                // 0..3
    const int lane = t & 63;
    const int l15 = lane & 15;
    const int kblk = lane >> 4;            // also the epilogue quad index

    const u8* gA = imgsT + (size_t)g * 8 * A_CHUNK;
    const u8* gB = capsT + (size_t)cg * 8 * B_CHUNK;

    // Each wave stages its QUARTER of A into abuf + its OWN 32-row B band.
    auto stage = [&](int kb, int abuf) {
        const u8* srcA = gA + (size_t)kb * A_CHUNK;
        char* dstA = smem + abuf * A1_OFF;
        {
            const int ub = wid * 288;
            #pragma unroll
            for (int jj = 0; jj < 4; ++jj) {
                const int u = ub + jj * 64 + lane;
                gload_lds16(srcA + u * 16, dstA + u * 16);
            }
            if (lane < 32) {
                const int u = ub + 256 + lane;
                gload_lds16(srcA + u * 16, dstA + u * 16);
            }
        }
        const u8* srcB = gB + (size_t)kb * B_CHUNK;
        char* dstB = smem + B_OFF;
        #pragma unroll
        for (int jj = 0; jj < 2; ++jj) {
            const int u = wid * 128 + jj * 64 + lane;
            gload_lds16(srcB + u * 16, dstB + u * 16);                  // h
            gload_lds16(srcB + 8192 + u * 16, dstB + 8192 + u * 16);    // l
        }
    };

    i32x4 accH[9][2], accC[9][2];
    #pragma unroll
    for (int mt = 0; mt < 9; ++mt)
        #pragma unroll
        for (int nt = 0; nt < 2; ++nt) {
            accH[mt][nt] = (i32x4){0, 0, 0, 0};
            accC[mt][nt] = (i32x4){0, 0, 0, 0};
        }

    stage(0, 0);

    const int blk16 = (kblk ^ ((l15 >> 1) & 3)) << 4;
    const int baseA = l15 * 64 + blk16;                // + mt*1024 ; h: +0, l: +9216
    const int baseB = (wid * 32 + l15) * 64 + blk16;   // + nt*1024 ; h: B_OFF, l: B_OFF+8192

    for (int kb = 0; kb < 8; ++kb) {
        asm volatile("s_waitcnt vmcnt(0)" ::: "memory");
        __builtin_amdgcn_sched_barrier(0);
        __builtin_amdgcn_s_barrier();
        __builtin_amdgcn_sched_barrier(0);

        char* curA = smem + (size_t)(kb & 1) * A1_OFF;

        // B -> registers (own band only); then own B region is dead.
        const i32x4 bh0 = *(const i32x4*)(smem + B_OFF + baseB);
        const i32x4 bl0 = *(const i32x4*)(smem + B_OFF + 8192 + baseB);
        const i32x4 bh1 = *(const i32x4*)(smem + B_OFF + baseB + 1024);
        const i32x4 bl1 = *(const i32x4*)(smem + B_OFF + 8192 + baseB + 1024);
        asm volatile("s_waitcnt lgkmcnt(0)" ::: "memory");
        __builtin_amdgcn_sched_barrier(0);

        if (kb < 7) stage(kb + 1, (kb + 1) & 1);

        __builtin_amdgcn_s_setprio(1);
        #pragma unroll
        for (int mt = 0; mt < 9; ++mt) {
            const i32x4 ah = *(const i32x4*)(curA + baseA + mt * 1024);
            const i32x4 al = *(const i32x4*)(curA + 9216 + baseA + mt * 1024);
            i32x4 lt0 = (i32x4){0, 0, 0, 0};
            i32x4 lt1 = (i32x4){0, 0, 0, 0};
            lt0 = __builtin_amdgcn_mfma_i32_16x16x64_i8(al, bl0, lt0, 0, 0, 0);
            lt1 = __builtin_amdgcn_mfma_i32_16x16x64_i8(al, bl1, lt1, 0, 0, 0);
            accH[mt][0] = __builtin_amdgcn_mfma_i32_16x16x64_i8(ah, bh0, accH[mt][0], 0, 0, 0);
            accH[mt][1] = __builtin_amdgcn_mfma_i32_16x16x64_i8(ah, bh1, accH[mt][1], 0, 0, 0);
            accC[mt][0] = __builtin_amdgcn_mfma_i32_16x16x64_i8(ah, bl0, accC[mt][0], 0, 0, 0);
            accC[mt][0] = __builtin_amdgcn_mfma_i32_16x16x64_i8(al, bh0, accC[mt][0], 0, 0, 0);
            accC[mt][1] = __builtin_amdgcn_mfma_i32_16x16x64_i8(ah, bl1, accC[mt][1], 0, 0, 0);
            accC[mt][1] = __builtin_amdgcn_mfma_i32_16x16x64_i8(al, bh1, accC[mt][1], 0, 0, 0);
            #pragma unroll
            for (int e = 0; e < 4; ++e) {
                accC[mt][0][e] += lt0[e] >> 8;   // truncation bias <= 1.2e-3 s-units
                accC[mt][1][e] += lt1[e] >> 8;
            }
        }
        __builtin_amdgcn_s_setprio(0);
    }

    __syncthreads();   // all LDS reads done; no outstanding staging

    // ---- stage Gram (4 imgs, fp32) into retired staging LDS
    float* sG = (float*)smem;
    {
        const float4* src = (const float4*)(G + (size_t)g * 4 * 1296);
        for (int idx = t; idx < 1296; idx += 256)
            ((float4*)sG)[idx] = src[idx];
    }
    __syncthreads();

    int ilen_[4];
    #pragma unroll
    for (int j = 0; j < 4; ++j) ilen_[j] = img_lens[g * 4 + j];

    #pragma unroll
    for (int nt = 0; nt < 2; ++nt) {
        const int col = wid * 32 + nt * 16 + l15;     // 0..127 cap-word col
        const int c = cg * 4 + (col >> 5);
        const int w = col & 31;
        const int clen = cap_lens[c];
        #pragma unroll
        for (int j = 0; j < 4; ++j) {
            const int mtb = (36 * j) >> 4;            // 0,2,4,6
            const int ilenj = ilen_[j];
            float tv0 = NEGV, tv1 = NEGV, tv2 = NEGV, tv3 = NEGV, tv4 = NEGV;
            #pragma unroll
            for (int dm = 0; dm < 3; ++dm) {
                #pragma unroll
                for (int e = 0; e < 4; ++e) {
                    const int mt = mtb + dm;
                    const int r = mt * 16 + kblk * 4 + e;
                    const int rr = r - 36 * j;
                    const float sval = (float)accH[mt][nt][e] * (10.f / 256.f)
                                     + (float)accC[mt][nt][e] * (10.f / 65536.f);
                    float v = NEGV;
                    if ((unsigned)rr < (unsigned)ilenj)
                        v = __uint_as_float((__float_as_uint(sval) & ~63u) | (u32)rr);
                    const bool c0 = v > tv0, c1 = v > tv1, c2 = v > tv2, c3 = v > tv3, c4 = v > tv4;
                    const float n4 = c4 ? (c3 ? tv3 : v) : tv4;
                    const float n3 = c3 ? (c2 ? tv2 : v) : tv3;
                    const float n2 = c2 ? (c1 ? tv1 : v) : tv2;
                    const float n1 = c1 ? (c0 ? tv0 : v) : tv1;
                    const float n0 = c0 ? v : tv0;
                    tv0 = n0; tv1 = n1; tv2 = n2; tv3 = n3; tv4 = n4;
                }
            }
            float ta[5] = {tv0, tv1, tv2, tv3, tv4};
            #pragma unroll
            for (int st = 0; st < 2; ++st) {
                const int dx = 16 << st;
                float tb[5];
                #pragma unroll
                for (int s = 0; s < 5; ++s) tb[s] = __shfl_xor(ta[s], dx);
                float na[5];
                #pragma unroll
                for (int k = 0; k < 5; ++k) {
                    float best = fmaxf(ta[k], tb[k]);
                    #pragma unroll
                    for (int i2 = 1; i2 <= k; ++i2)
                        best = fmaxf(best, fminf(ta[i2 - 1], tb[k - i2]));
                    na[k] = best;
                }
                #pragma unroll
                for (int s = 0; s < 5; ++s) ta[s] = na[s];
            }
            const float m = ta[0];
            const float p0 = 1.f;
            const float p1 = __expf(ta[1] - m);
            const float p2 = __expf(ta[2] - m);
            const float p3 = __expf(ta[3] - m);
            const float p4 = __expf(ta[4] - m);
            const float sum = p0 + p1 + p2 + p3 + p4;
            const float num = p0 * ta[0] + p1 * ta[1] + p2 * ta[2] + p3 * ta[3] + p4 * ta[4];
            const int r0 = __float_as_uint(ta[0]) & 63;
            const int r1 = __float_as_uint(ta[1]) & 63;
            const int r2 = __float_as_uint(ta[2]) & 63;
            const int r3 = __float_as_uint(ta[3]) & 63;
            const int r4 = __float_as_uint(ta[4]) & 63;
            const float* gj = sG + j * 1296;
            const float pa = (kblk == 0) ? p0 : (kblk == 1) ? p1 : (kblk == 2) ? p2 : p3;
            const int   ra = (kblk == 0) ? r0 : (kblk == 1) ? r1 : (kblk == 2) ? r2 : r3;
            const float* grow = gj + ra * 36;
            float part = pa * (p0 * grow[r0] + p1 * grow[r1] + p2 * grow[r2]
                             + p3 * grow[r3] + p4 * grow[r4]);
            if (kblk == 0) {
                const float* grow4 = gj + r4 * 36;
                part += p4 * (p0 * grow4[r0] + p1 * grow4[r1] + p2 * grow4[r2]
                            + p3 * grow4[r3] + p4 * grow4[r4]);
            }
            part += __shfl_xor(part, 16);
            part += __shfl_xor(part, 32);
            if (kblk == j) {
                float result = -1.f;
                if (w < clen) {
                    const float inv = __builtin_amdgcn_rcpf(sum);
                    const float a_ = 0.1f * num * inv;
                    const float den = __builtin_amdgcn_sqrtf(part) * inv + (-1e-8f);
                    result = a_ * __builtin_amdgcn_rcpf(den);
                }
                out[((size_t)(g * 4 + j) * N_CAP + c) * MAX_W + w] = result;
            }
        }
    }
}

extern "C" void kernel_launch(void* const* d_in, const int* in_sizes, int n_in,
                              void* d_out, int out_size, void* d_ws, size_t ws_size,
                              hipStream_t stream) {
    const float* imgs     = (const float*)d_in[0];
    const float* caps     = (const float*)d_in[1];
    const int*   img_lens = (const int*)d_in[2];
    const int*   cap_lens = (const int*)d_in[3];
    float* out = (float*)d_out;

    // d_ws layout
    float* G  = (float*)d_ws;                          // 128*1296*4 = 663552 B
    u8* imgsT = (u8*)d_ws + 663552;                    // 32*8*18432 = 4718592 B
    u8* capsT = imgsT + (size_t)32 * 8 * A_CHUNK;      // 32*8*16384 = 4194304 B

    hipFuncSetAttribute((const void*)vsc_mfma_kernel,
                        hipFuncAttributeMaxDynamicSharedMemorySize, LDS_BYTES);

    convert_kernel<<<4352, 256, 0, stream>>>(imgs, caps, imgsT, capsT);
    gram_i8_kernel<<<N_IMG, 256, 0, stream>>>(imgsT, G);
    vsc_mfma_kernel<<<1024, 256, LDS_BYTES, stream>>>(imgsT, capsT, img_lens, cap_lens, G, out);
}